// Round 10
// baseline (485.394 us; speedup 1.0000x reference)
//
#include <hip/hip_runtime.h>
#include <hip/hip_bf16.h>

// ---------------------------------------------------------------------------
// myGRUCell low-rank, R10: max-concurrency, barrier-minimal.
//   zerok: zero A12f accumulator (16 MB)
//   prep : pack weights bf16 transposed into ws
//   k1   : A12f[B][128] += [x@W | h@U] (f32 atomics; split-K x4; grid 4096,
//          128 thr, NO LDS, NO barriers, 16 waves/CU)
//   k2f  : fused rhU + gates + out (block = 16 rows, 2 col-half waves,
//          one barrier for rhU pair-reduce; grid 2048)
// ws layout: shorts [0..524288) = Wt[64][1024] | Ut | P1t[1024][128] | P2t |
//            P3t;  bytes [1048576, +16MB) = A12f f32 [32768][128].
// ---------------------------------------------------------------------------

typedef __attribute__((ext_vector_type(8))) short short8;
typedef __attribute__((ext_vector_type(4))) float f32x4;
typedef __attribute__((ext_vector_type(4))) float f4;

#define WS_UT   65536
#define WS_P1T  131072
#define WS_P2T  262144
#define WS_P3T  393216
#define A12F_BYTE_OFF 1048576

__device__ __forceinline__ short f2bf(float f) {
  unsigned u = __builtin_bit_cast(unsigned, f);
  u += 0x7FFFu + ((u >> 16) & 1u);          // round-nearest-even
  return (short)(u >> 16);
}
__device__ __forceinline__ short8 cvt8(f4 a, f4 b) {
  short8 r;
#pragma unroll
  for (int j = 0; j < 4; ++j) { r[j] = f2bf(a[j]); r[4 + j] = f2bf(b[j]); }
  return r;
}
__device__ __forceinline__ f32x4 mfma16(short8 a, short8 b, f32x4 c) {
  return __builtin_amdgcn_mfma_f32_16x16x32_bf16(a, b, c, 0, 0, 0);
}
__device__ __forceinline__ short8 ldg8(const short* p) {
  return *reinterpret_cast<const short8*>(p);
}
__device__ __forceinline__ f4 ldf4(const float* p) {
  return *reinterpret_cast<const f4*>(p);
}

// [16][64]-short per-wave transpose buffer, XOR-swizzled 16B granules
__device__ __forceinline__ void wr64(short* b, int row, int col, short v) {
  b[row * 64 + (col ^ ((row & 7) << 3))] = v;
}
__device__ __forceinline__ short8 rd64(const short* b, int row, int col) {
  return *reinterpret_cast<const short8*>(b + row * 64 + (col ^ ((row & 7) << 3)));
}

#define LOG2E 1.4426950408889634f
__device__ __forceinline__ float sigm_f(float v) {
  return __builtin_amdgcn_rcpf(1.f + __builtin_amdgcn_exp2f(-v * LOG2E));
}
__device__ __forceinline__ float tanh_f(float v) {
  float t = __builtin_amdgcn_exp2f(v * (2.f * LOG2E));
  return 1.f - 2.f * __builtin_amdgcn_rcpf(t + 1.f);
}

// ---------------------------------------------------------------------------
__global__ void zerok(float* __restrict__ p) {
  const int i = blockIdx.x * blockDim.x + threadIdx.x;
  f4 z = {0.f, 0.f, 0.f, 0.f};
  *reinterpret_cast<f4*>(p + (size_t)i * 8) = z;
  *reinterpret_cast<f4*>(p + (size_t)i * 8 + 4) = z;
}

// ---------------------------------------------------------------------------
__global__ void prep_kernel(const float* __restrict__ W,  const float* __restrict__ W1,
                            const float* __restrict__ W2, const float* __restrict__ W3,
                            const float* __restrict__ U,  const float* __restrict__ U1,
                            const float* __restrict__ U2, const float* __restrict__ U3,
                            short* __restrict__ ws) {
  int i = blockIdx.x * blockDim.x + threadIdx.x;
  float v;
  if (i < 65536) {
    int n = i >> 10, k = i & 1023;
    v = W[k * 64 + n];
  } else if (i < 131072) {
    int j = i - 65536;
    int n = j >> 10, k = j & 1023;
    v = U[k * 64 + n];
  } else {
    int j = i - 131072;
    int sel = j >> 17;
    int jj = j & 131071;
    int n = jj >> 7, k = jj & 127;
    const float* Wk = sel == 0 ? W1 : sel == 1 ? W2 : W3;
    const float* Uk = sel == 0 ? U1 : sel == 1 ? U2 : U3;
    v = (k < 64) ? Wk[k * 1024 + n] : Uk[(k - 64) * 1024 + n];
  }
  ws[i] = f2bf(v);
}

// ---------------------------------------------------------------------------
// k1: A12f += [x@W | h@U].  Grid 4096 x 128 thr: block = 32 rows x K-chunk 256.
// No LDS, no barriers; f32 atomic accumulate (A12f pre-zeroed).
// ---------------------------------------------------------------------------
__global__ __launch_bounds__(128, 4) void k1_a12(
    const float* __restrict__ x, const float* __restrict__ h,
    const short* __restrict__ ws, float* __restrict__ A12f) {
  const int tid = threadIdx.x;
  const int w = tid >> 6, l = tid & 63, l15 = l & 15, lg = l >> 4;
  const int rb = blockIdx.x >> 2;     // 1024 row-blocks of 32
  const int c  = blockIdx.x & 3;      // K-chunk
  const int sr = rb * 32 + w * 16;
  const int kb = c * 256;
  const short* Wt = ws;
  const short* Ut = ws + WS_UT;

  const float* xr = x + (size_t)(sr + l15) * 1024 + kb + lg * 8;
  const float* hr = h + (size_t)(sr + l15) * 1024 + kb + lg * 8;

  f32x4 accX[4] = {}, accH[4] = {};
#pragma unroll
  for (int ks = 0; ks < 8; ++ks) {
    f4 xa = ldf4(xr + ks * 32), xb2 = ldf4(xr + ks * 32 + 4);
    f4 ha = ldf4(hr + ks * 32), hb2 = ldf4(hr + ks * 32 + 4);
    short8 ax = cvt8(xa, xb2), ah = cvt8(ha, hb2);
    const int kk = kb + ks * 32 + lg * 8;
#pragma unroll
    for (int cf = 0; cf < 4; ++cf) {
      accX[cf] = mfma16(ax, ldg8(Wt + (size_t)(cf * 16 + l15) * 1024 + kk), accX[cf]);
      accH[cf] = mfma16(ah, ldg8(Ut + (size_t)(cf * 16 + l15) * 1024 + kk), accH[cf]);
    }
  }
#pragma unroll
  for (int cf = 0; cf < 4; ++cf)
#pragma unroll
    for (int j = 0; j < 4; ++j) {
      const size_t row = (size_t)(sr + lg * 4 + j) * 128;
      atomicAdd(&A12f[row + cf * 16 + l15], accX[cf][j]);
      atomicAdd(&A12f[row + 64 + cf * 16 + l15], accH[cf][j]);
    }
}

// ---------------------------------------------------------------------------
// k2f: rhU (in-register) then gates + out.  Block = 16 rows, 2 waves split by
// column half; one barrier (rhU pair-reduce).  Grid 2048 x 128 thr.
// ---------------------------------------------------------------------------
__global__ __launch_bounds__(128, 3) void k2f(
    const float* __restrict__ h,
    const float* __restrict__ u1d, const float* __restrict__ u2d,
    const float* __restrict__ u3d,
    const float* __restrict__ biasR, const float* __restrict__ biasZ,
    const float* __restrict__ biasU,
    const short* __restrict__ ws, const float* __restrict__ A12f,
    float* __restrict__ out) {
  const short* Ut  = ws + WS_UT;
  const short* P1t = ws + WS_P1T;
  const short* P2t = ws + WS_P2T;
  const short* P3t = ws + WS_P3T;

  __shared__ __align__(16) short sT[2][16 * 64];    // per-wave rh transpose
  __shared__ __align__(16) float sRed[2][16 * 64];  // rhU partials

  const int tid = threadIdx.x;
  const int w = tid >> 6, l = tid & 63, l15 = l & 15, lg = l >> 4;
  const int sr = blockIdx.x * 16;

  // a12 fragments from f32 accumulator (cvt at the same point as before)
  short8 a12[4];
#pragma unroll
  for (int k0 = 0; k0 < 4; ++k0) {
    const float* p = A12f + (size_t)(sr + l15) * 128 + k0 * 32 + lg * 8;
    a12[k0] = cvt8(ldf4(p), ldf4(p + 4));
  }

  // ---- phase A: partial rhU over this wave's 8 K-slices (tiles w*8..w*8+7)
  f32x4 accU[4] = {};
#pragma unroll 1
  for (int t = 0; t < 8; ++t) {
    const int n0 = (w * 8 + t) * 64;

    float hv[4][4];
#pragma unroll
    for (int cf = 0; cf < 4; ++cf)
#pragma unroll
      for (int j = 0; j < 4; ++j)
        hv[cf][j] = h[(size_t)(sr + lg * 4 + j) * 1024 + n0 + cf * 16 + l15];

    f32x4 accR[4] = {};
#pragma unroll
    for (int ks = 0; ks < 4; ++ks)
#pragma unroll
      for (int cf = 0; cf < 4; ++cf)
        accR[cf] = mfma16(a12[ks],
            ldg8(P1t + (size_t)(n0 + cf * 16 + l15) * 128 + ks * 32 + lg * 8),
            accR[cf]);

#pragma unroll
    for (int cf = 0; cf < 4; ++cf) {
      const int cc = n0 + cf * 16 + l15;
      const float d1 = u1d[cc], b_r = biasR[cc];
#pragma unroll
      for (int j = 0; j < 4; ++j) {
        float rv = sigm_f(accR[cf][j] + hv[cf][j] * d1 + b_r);
        wr64(&sT[w][0], lg * 4 + j, cf * 16 + l15, f2bf(rv * hv[cf][j]));
      }
    }
    // wave-coherent RAW through LDS (lgkmcnt only; R5-R8 proven)
    short8 arh0 = rd64(&sT[w][0], l15, lg * 8);
    short8 arh1 = rd64(&sT[w][0], l15, 32 + lg * 8);
#pragma unroll
    for (int cf = 0; cf < 4; ++cf) {
      accU[cf] = mfma16(arh0, ldg8(Ut + (size_t)(cf * 16 + l15) * 1024 + n0 + lg * 8), accU[cf]);
      accU[cf] = mfma16(arh1, ldg8(Ut + (size_t)(cf * 16 + l15) * 1024 + n0 + 32 + lg * 8), accU[cf]);
    }
  }

  // ---- pair-reduce rhU partials across the two waves
#pragma unroll
  for (int cf = 0; cf < 4; ++cf)
#pragma unroll
    for (int j = 0; j < 4; ++j) {
      int row = lg * 4 + j, col = cf * 16 + l15;
      sRed[w][row * 64 + (col ^ ((row & 7) << 2))] = accU[cf][j];
    }
  __syncthreads();

  short8 arhu[2];
  {
    const float* f0 = &sRed[0][0];
    const float* f1 = &sRed[1][0];
    const int sw = (l15 & 7) << 2;
#pragma unroll
    for (int kk = 0; kk < 2; ++kk) {
      const int c0 = kk * 32 + lg * 8;
      f4 pa = *reinterpret_cast<const f4*>(f0 + l15 * 64 + (c0 ^ sw));
      f4 pb = *reinterpret_cast<const f4*>(f0 + l15 * 64 + ((c0 + 4) ^ sw));
      f4 qa = *reinterpret_cast<const f4*>(f1 + l15 * 64 + (c0 ^ sw));
      f4 qb = *reinterpret_cast<const f4*>(f1 + l15 * 64 + ((c0 + 4) ^ sw));
      arhu[kk] = cvt8(pa + qa, pb + qb);
    }
  }

  // ---- phase B: gates + out for this wave's 8 column tiles
#pragma unroll 1
  for (int t = 0; t < 8; ++t) {
    const int n0 = (w * 8 + t) * 64;

    float hv[4][4];
#pragma unroll
    for (int cf = 0; cf < 4; ++cf)
#pragma unroll
      for (int j = 0; j < 4; ++j)
        hv[cf][j] = h[(size_t)(sr + lg * 4 + j) * 1024 + n0 + cf * 16 + l15];

    f32x4 aR[4] = {}, aZ[4] = {}, aC[4] = {};
#pragma unroll
    for (int ks = 0; ks < 4; ++ks) {
      const short8 a3 = (ks < 2) ? a12[ks] : arhu[ks - 2];
#pragma unroll
      for (int cf = 0; cf < 4; ++cf) {
        const size_t bo = (size_t)(n0 + cf * 16 + l15) * 128 + ks * 32 + lg * 8;
        aR[cf] = mfma16(a12[ks], ldg8(P1t + bo), aR[cf]);
        aZ[cf] = mfma16(a12[ks], ldg8(P2t + bo), aZ[cf]);
        aC[cf] = mfma16(a3,      ldg8(P3t + bo), aC[cf]);
      }
    }

#pragma unroll
    for (int cf = 0; cf < 4; ++cf) {
      const int cc = n0 + cf * 16 + l15;
      const float d1 = u1d[cc], d2 = u2d[cc], d3 = u3d[cc];
      const float b_r = biasR[cc], b_z = biasZ[cc], b_u = biasU[cc];
#pragma unroll
      for (int j = 0; j < 4; ++j) {
        const size_t gi = (size_t)(sr + lg * 4 + j) * 1024 + cc;
        const float hvj = hv[cf][j];
        float rv = sigm_f(aR[cf][j] + hvj * d1 + b_r);
        float zv = sigm_f(aZ[cf][j] + hvj * d2 + b_z);
        float cv = tanh_f(aC[cf][j] + rv * hvj * d3 + b_u);
        out[gi] = zv * hvj + (1.f - zv) * cv;
      }
    }
  }
}

extern "C" void kernel_launch(void* const* d_in, const int* in_sizes, int n_in,
                              void* d_out, int out_size, void* d_ws, size_t ws_size,
                              hipStream_t stream) {
  const float* x   = (const float*)d_in[0];
  const float* h   = (const float*)d_in[1];
  const float* W   = (const float*)d_in[2];
  const float* W1  = (const float*)d_in[3];
  const float* W2  = (const float*)d_in[4];
  const float* W3  = (const float*)d_in[5];
  const float* U   = (const float*)d_in[6];
  const float* U1  = (const float*)d_in[7];
  const float* U2  = (const float*)d_in[8];
  const float* U3  = (const float*)d_in[9];
  const float* u1d = (const float*)d_in[10];
  const float* u2d = (const float*)d_in[11];
  const float* u3d = (const float*)d_in[12];
  const float* bR  = (const float*)d_in[13];
  const float* bZ  = (const float*)d_in[14];
  const float* bU  = (const float*)d_in[15];
  short* ws   = (short*)d_ws;
  float* A12f = (float*)((char*)d_ws + A12F_BYTE_OFF);

  zerok<<<2048, 256, 0, stream>>>(A12f);          // 16 MB zero (4.2M floats)
  prep_kernel<<<2048, 256, 0, stream>>>(W, W1, W2, W3, U, U1, U2, U3, ws);
  k1_a12<<<4096, 128, 0, stream>>>(x, h, ws, A12f);
  k2f<<<2048, 128, 0, stream>>>(h, u1d, u2d, u3d, bR, bZ, bU, ws, A12f, (float*)d_out);
}

// Round 11
// 399.874 us; speedup vs baseline: 1.2139x; 1.2139x over previous
//
#include <hip/hip_runtime.h>
#include <hip/hip_bf16.h>

// ---------------------------------------------------------------------------
// myGRUCell low-rank, R11.
//   prep: pack weights bf16 transposed into ws
//   k1  : A12 = [x@W | h@U] bf16.  R8 structure, chunk 64 -> 32KB LDS ->
//         4 blocks/CU (16 waves/CU), VWAIT(4) pipeline.  grid 1024.
//   k23 : rhU = (sigmoid(pre_r)*h) @ U.  R8 byte-identical.  grid 512.
//   k4  : out = z*h+(1-z)*tanh(c).  Max-TLP: wave = 16 rows x 64 cols,
//         32768 independent waves (grid 8192), no LDS, no barriers.
// ws layout (shorts): Wt[64][1024] | Ut | P1t[1024][128] | P2t | P3t |
//                     A12[32768][128] | rhU[32768][64]
// ---------------------------------------------------------------------------

typedef __attribute__((ext_vector_type(8))) short short8;
typedef __attribute__((ext_vector_type(4))) float f32x4;
typedef __attribute__((ext_vector_type(4))) float f4;

#define WS_UT   65536
#define WS_P1T  131072
#define WS_P2T  262144
#define WS_P3T  393216
#define WS_A12  524288
#define WS_RHU  4718592

__device__ __forceinline__ short f2bf(float f) {
  unsigned u = __builtin_bit_cast(unsigned, f);
  u += 0x7FFFu + ((u >> 16) & 1u);          // round-nearest-even
  return (short)(u >> 16);
}
__device__ __forceinline__ short8 cvt8(f4 a, f4 b) {
  short8 r;
#pragma unroll
  for (int j = 0; j < 4; ++j) { r[j] = f2bf(a[j]); r[4 + j] = f2bf(b[j]); }
  return r;
}
__device__ __forceinline__ f32x4 mfma16(short8 a, short8 b, f32x4 c) {
  return __builtin_amdgcn_mfma_f32_16x16x32_bf16(a, b, c, 0, 0, 0);
}
__device__ __forceinline__ short8 ldg8(const short* p) {
  return *reinterpret_cast<const short8*>(p);
}
__device__ __forceinline__ f4 ldf4(const float* p) {
  return *reinterpret_cast<const f4*>(p);
}

// async 16B global->LDS
__device__ __forceinline__ void cp16(void* l, const void* g) {
  __builtin_amdgcn_global_load_lds(
      (const __attribute__((address_space(1))) void*)g,
      (__attribute__((address_space(3))) void*)l, 16, 0, 0);
}
#define VWAIT(N) do { asm volatile("s_waitcnt vmcnt(" #N ")" ::: "memory"); \
                      __builtin_amdgcn_sched_barrier(0); } while (0)

// [16][64]-short per-wave transpose buffer, XOR-swizzled 16B granules
__device__ __forceinline__ void wr64(short* b, int row, int col, short v) {
  b[row * 64 + (col ^ ((row & 7) << 3))] = v;
}
__device__ __forceinline__ short8 rd64(const short* b, int row, int col) {
  return *reinterpret_cast<const short8*>(b + row * 64 + (col ^ ((row & 7) << 3)));
}

#define LOG2E 1.4426950408889634f
__device__ __forceinline__ float sigm_f(float v) {
  return __builtin_amdgcn_rcpf(1.f + __builtin_amdgcn_exp2f(-v * LOG2E));
}
__device__ __forceinline__ float tanh_f(float v) {
  float t = __builtin_amdgcn_exp2f(v * (2.f * LOG2E));
  return 1.f - 2.f * __builtin_amdgcn_rcpf(t + 1.f);
}

// ---------------------------------------------------------------------------
__global__ void prep_kernel(const float* __restrict__ W,  const float* __restrict__ W1,
                            const float* __restrict__ W2, const float* __restrict__ W3,
                            const float* __restrict__ U,  const float* __restrict__ U1,
                            const float* __restrict__ U2, const float* __restrict__ U3,
                            short* __restrict__ ws) {
  int i = blockIdx.x * blockDim.x + threadIdx.x;
  float v;
  if (i < 65536) {
    int n = i >> 10, k = i & 1023;
    v = W[k * 64 + n];
  } else if (i < 131072) {
    int j = i - 65536;
    int n = j >> 10, k = j & 1023;
    v = U[k * 64 + n];
  } else {
    int j = i - 131072;
    int sel = j >> 17;
    int jj = j & 131071;
    int n = jj >> 7, k = jj & 127;
    const float* Wk = sel == 0 ? W1 : sel == 1 ? W2 : W3;
    const float* Uk = sel == 0 ? U1 : sel == 1 ? U2 : U3;
    v = (k < 64) ? Wk[k * 1024 + n] : Uk[(k - 64) * 1024 + n];
  }
  ws[i] = f2bf(v);
}

// ---------------------------------------------------------------------------
// k1: A12 = [x@W | h@U].  Block 32 rows, 4 waves: wave = (matrix m, row half).
// 16 K-chunks of 64 f32 staged to LDS (32 KB total), VWAIT(4) depth-2.
// grid 1024, 4 blocks/CU.
// ---------------------------------------------------------------------------
__global__ __launch_bounds__(256, 4) void k1_a12(
    const float* __restrict__ x, const float* __restrict__ h,
    const short* __restrict__ ws, short* __restrict__ A12) {
  __shared__ __align__(16) float sS[2][4][16 * 64];   // [buf][wave][16r][64f]

  const int tid = threadIdx.x;
  const int w = tid >> 6, l = tid & 63, l15 = l & 15, lg = l >> 4;
  const int m = w >> 1, half = w & 1;
  const int sr = blockIdx.x * 32 + half * 16;
  const float* src = m ? h : x;
  const short* Bt  = ws + m * WS_UT;

  const int srow = l >> 4;            // 0..3: row within 4-row issue
  const int slin = (l & 15) * 16;     // byte within 256B row

  auto STAGE = [&](int c, int b) {
#pragma unroll
    for (int i = 0; i < 4; ++i) {
      int r = i * 4 + srow;
      int kb = slin ^ ((r & 7) << 4);  // pre-swizzled source (rule 21)
      cp16((char*)&sS[b][w][0] + i * 1024,
           (const char*)(src + (size_t)(sr + r) * 1024 + c * 64) + kb);
    }
  };

  f32x4 acc[4] = {};
  STAGE(0, 0);
#pragma unroll 1
  for (int c = 0; c < 16; ++c) {
    short8 bw[2][4];
#pragma unroll
    for (int ks = 0; ks < 2; ++ks)
#pragma unroll
      for (int cf = 0; cf < 4; ++cf)
        bw[ks][cf] = ldg8(Bt + (size_t)(cf * 16 + l15) * 1024 + c * 64 + ks * 32 + lg * 8);
    if (c < 15) { STAGE(c + 1, (c + 1) & 1); VWAIT(4); }
    else        { VWAIT(0); }
    const char* Bb = (const char*)&sS[c & 1][w][0];
    const int s = (l15 & 7) << 4;
#pragma unroll
    for (int ks = 0; ks < 2; ++ks) {
      const int kb0 = (ks * 32 + lg * 8) * 4;
      f4 pa = *(const f4*)(Bb + l15 * 256 + (kb0 ^ s));
      f4 pb = *(const f4*)(Bb + l15 * 256 + ((kb0 + 16) ^ s));
      short8 av = cvt8(pa, pb);
#pragma unroll
      for (int cf = 0; cf < 4; ++cf) acc[cf] = mfma16(av, bw[ks][cf], acc[cf]);
    }
  }
#pragma unroll
  for (int cf = 0; cf < 4; ++cf)
#pragma unroll
    for (int j = 0; j < 4; ++j)
      A12[(size_t)(sr + lg * 4 + j) * 128 + m * 64 + cf * 16 + l15] = f2bf(acc[cf][j]);
}

// ---------------------------------------------------------------------------
// k23 (R8, unchanged): rhU = (sigmoid(A12@P1 + h*U1d + bR) * h) @ U.
// ---------------------------------------------------------------------------
__global__ __launch_bounds__(256, 2) void k23_rhu(
    const float* __restrict__ h, const float* __restrict__ u1d,
    const float* __restrict__ biasR,
    const short* __restrict__ ws, const short* __restrict__ A12,
    short* __restrict__ rhU) {
  const short* Ut  = ws + WS_UT;
  const short* P1t = ws + WS_P1T;
  __shared__ __align__(16) float hS[2][4][16 * 64];
  __shared__ __align__(16) short sT[4][16 * 64];

  const int tid = threadIdx.x;
  const int w = tid >> 6, l = tid & 63, l15 = l & 15, lg = l >> 4;
  const int sr = blockIdx.x * 64 + w * 16;

  const int srow = l >> 4;
  const int slin = (l & 15) * 16;

  auto STAGE = [&](int t, int b) {
#pragma unroll
    for (int i = 0; i < 4; ++i) {
      int r = i * 4 + srow;
      int kb = slin ^ ((r & 7) << 4);
      cp16((char*)&hS[b][w][0] + i * 1024,
           (const char*)(h + (size_t)(sr + r) * 1024 + t * 64) + kb);
    }
  };

  short8 a12[4];
#pragma unroll
  for (int k0 = 0; k0 < 4; ++k0)
    a12[k0] = ldg8(A12 + (size_t)(sr + l15) * 128 + k0 * 32 + lg * 8);

  f32x4 accU[4] = {};
  STAGE(0, 0);
#pragma unroll 1
  for (int tt = 0; tt < 16; ++tt) {
    const int n0 = tt * 64;
    short8 b1[4][4], bu[2][4];
    float d1_[4], br_[4];
#pragma unroll
    for (int ks = 0; ks < 4; ++ks)
#pragma unroll
      for (int cf = 0; cf < 4; ++cf)
        b1[ks][cf] = ldg8(P1t + (size_t)(n0 + cf * 16 + l15) * 128 + ks * 32 + lg * 8);
#pragma unroll
    for (int kk = 0; kk < 2; ++kk)
#pragma unroll
      for (int cf = 0; cf < 4; ++cf)
        bu[kk][cf] = ldg8(Ut + (size_t)(cf * 16 + l15) * 1024 + n0 + kk * 32 + lg * 8);
#pragma unroll
    for (int cf = 0; cf < 4; ++cf) {
      d1_[cf] = u1d[n0 + cf * 16 + l15];
      br_[cf] = biasR[n0 + cf * 16 + l15];
    }
    if (tt < 15) { STAGE(tt + 1, (tt + 1) & 1); VWAIT(4); }
    else         { VWAIT(0); }
    const char* H = (const char*)&hS[tt & 1][w][0];

    float hv[4][4];
#pragma unroll
    for (int cf = 0; cf < 4; ++cf)
#pragma unroll
      for (int j = 0; j < 4; ++j) {
        int rr = lg * 4 + j;
        hv[cf][j] = *(const float*)(H + rr * 256 + ((cf * 64 + l15 * 4) ^ ((rr & 7) << 4)));
      }
    f32x4 accR[4] = {};
#pragma unroll
    for (int ks = 0; ks < 4; ++ks)
#pragma unroll
      for (int cf = 0; cf < 4; ++cf) accR[cf] = mfma16(a12[ks], b1[ks][cf], accR[cf]);
#pragma unroll
    for (int cf = 0; cf < 4; ++cf)
#pragma unroll
      for (int j = 0; j < 4; ++j) {
        float rv = sigm_f(accR[cf][j] + hv[cf][j] * d1_[cf] + br_[cf]);
        wr64(&sT[w][0], lg * 4 + j, cf * 16 + l15, f2bf(rv * hv[cf][j]));
      }
    short8 arh0 = rd64(&sT[w][0], l15, lg * 8);
    short8 arh1 = rd64(&sT[w][0], l15, 32 + lg * 8);
#pragma unroll
    for (int cf = 0; cf < 4; ++cf) accU[cf] = mfma16(arh0, bu[0][cf], accU[cf]);
#pragma unroll
    for (int cf = 0; cf < 4; ++cf) accU[cf] = mfma16(arh1, bu[1][cf], accU[cf]);
  }
#pragma unroll
  for (int cf = 0; cf < 4; ++cf)
#pragma unroll
    for (int j = 0; j < 4; ++j)
      rhU[(size_t)(sr + lg * 4 + j) * 64 + cf * 16 + l15] = f2bf(accU[cf][j]);
}

// ---------------------------------------------------------------------------
// k4 (R11): out = z*h + (1-z)*tanh(pre_c).  Wave = 16 rows x 64 cols; 32768
// independent waves; no LDS, no barriers.  grid 8192 x 256, XCD-swizzled.
// ---------------------------------------------------------------------------
__global__ __launch_bounds__(256, 4) void k4_out(
    const float* __restrict__ h,
    const float* __restrict__ u1d, const float* __restrict__ u2d,
    const float* __restrict__ u3d,
    const float* __restrict__ biasR, const float* __restrict__ biasZ,
    const float* __restrict__ biasU,
    const short* __restrict__ ws, const short* __restrict__ A12,
    const short* __restrict__ rhU, float* __restrict__ out) {
  const short* P1t = ws + WS_P1T;
  const short* P2t = ws + WS_P2T;
  const short* P3t = ws + WS_P3T;

  // bijective XCD swizzle (8192 % 8 == 0): contiguous 1024-block chunk per XCD
  const int b = (blockIdx.x & 7) * 1024 + (blockIdx.x >> 3);

  const int tid = threadIdx.x;
  const int w = tid >> 6, l = tid & 63, l15 = l & 15, lg = l >> 4;
  const int gw = b * 4 + w;           // 0..32767
  const int sr = (gw >> 4) * 16;      // 16-row strip
  const int n0 = (gw & 15) * 64;      // 64-col tile

  short8 a12[4], arhu[2];
#pragma unroll
  for (int k0 = 0; k0 < 4; ++k0)
    a12[k0] = ldg8(A12 + (size_t)(sr + l15) * 128 + k0 * 32 + lg * 8);
#pragma unroll
  for (int kk = 0; kk < 2; ++kk)
    arhu[kk] = ldg8(rhU + (size_t)(sr + l15) * 64 + kk * 32 + lg * 8);

  f32x4 aR[4] = {}, aZ[4] = {}, aC[4] = {};
#pragma unroll
  for (int ks = 0; ks < 4; ++ks) {
    const short8 a3 = (ks < 2) ? a12[ks] : arhu[ks - 2];
#pragma unroll
    for (int cf = 0; cf < 4; ++cf) {
      const size_t bo = (size_t)(n0 + cf * 16 + l15) * 128 + ks * 32 + lg * 8;
      aR[cf] = mfma16(a12[ks], ldg8(P1t + bo), aR[cf]);
      aZ[cf] = mfma16(a12[ks], ldg8(P2t + bo), aZ[cf]);
      aC[cf] = mfma16(a3,      ldg8(P3t + bo), aC[cf]);
    }
  }

#pragma unroll
  for (int cf = 0; cf < 4; ++cf) {
    const int cc = n0 + cf * 16 + l15;
    const float d1 = u1d[cc], d2 = u2d[cc], d3 = u3d[cc];
    const float b_r = biasR[cc], b_z = biasZ[cc], b_u = biasU[cc];
#pragma unroll
    for (int j = 0; j < 4; ++j) {
      const size_t gi = (size_t)(sr + lg * 4 + j) * 1024 + cc;
      const float hvj = h[gi];
      float rv = sigm_f(aR[cf][j] + hvj * d1 + b_r);
      float zv = sigm_f(aZ[cf][j] + hvj * d2 + b_z);
      float cv = tanh_f(aC[cf][j] + rv * hvj * d3 + b_u);
      out[gi] = zv * hvj + (1.f - zv) * cv;
    }
  }
}

extern "C" void kernel_launch(void* const* d_in, const int* in_sizes, int n_in,
                              void* d_out, int out_size, void* d_ws, size_t ws_size,
                              hipStream_t stream) {
  const float* x   = (const float*)d_in[0];
  const float* h   = (const float*)d_in[1];
  const float* W   = (const float*)d_in[2];
  const float* W1  = (const float*)d_in[3];
  const float* W2  = (const float*)d_in[4];
  const float* W3  = (const float*)d_in[5];
  const float* U   = (const float*)d_in[6];
  const float* U1  = (const float*)d_in[7];
  const float* U2  = (const float*)d_in[8];
  const float* U3  = (const float*)d_in[9];
  const float* u1d = (const float*)d_in[10];
  const float* u2d = (const float*)d_in[11];
  const float* u3d = (const float*)d_in[12];
  const float* bR  = (const float*)d_in[13];
  const float* bZ  = (const float*)d_in[14];
  const float* bU  = (const float*)d_in[15];
  short* ws  = (short*)d_ws;
  short* A12 = ws + WS_A12;
  short* rhU = ws + WS_RHU;

  prep_kernel<<<2048, 256, 0, stream>>>(W, W1, W2, W3, U, U1, U2, U3, ws);
  k1_a12<<<1024, 256, 0, stream>>>(x, h, ws, A12);
  k23_rhu<<<512, 256, 0, stream>>>(h, u1d, bR, ws, A12, rhU);
  k4_out<<<8192, 256, 0, stream>>>(h, u1d, u2d, u3d, bR, bZ, bU, ws, A12, rhU, (float*)d_out);
}

// Round 12
// 313.700 us; speedup vs baseline: 1.5473x; 1.2747x over previous
//
#include <hip/hip_runtime.h>
#include <hip/hip_bf16.h>

// ---------------------------------------------------------------------------
// myGRUCell low-rank, R12: best-of composition.
//   zerok: zero A12f (16 MB)
//   prep : pack weights bf16 transposed into ws
//   k1   : A12f += [x@W | h@U]  (R10 split-K x4, f32 atomics, no LDS,
//          grid 4096 x 128 thr -> 16k waves)           [proven ~85 us]
//   k23  : rhU = (sigmoid(pre_r)*h) @ U  (R8 structure; A12 read as f32)
//   k4   : out = z*h+(1-z)*tanh(c)  (R8 stationary-B; A12 read as f32)
// ws layout: shorts [0..524288) = Wt[64][1024] | Ut | P1t[1024][128] | P2t |
//   P3t;  bytes [1048576, +16MB) = A12f f32 [32768][128];
//   shorts from 8912896 = rhU bf16 [32768][64].   Total ws use: 21 MB.
// ---------------------------------------------------------------------------

typedef __attribute__((ext_vector_type(8))) short short8;
typedef __attribute__((ext_vector_type(4))) float f32x4;
typedef __attribute__((ext_vector_type(4))) float f4;

#define WS_UT   65536
#define WS_P1T  131072
#define WS_P2T  262144
#define WS_P3T  393216
#define A12F_BYTE_OFF 1048576
#define WS_RHU_SHORT  8912896

__device__ __forceinline__ short f2bf(float f) {
  unsigned u = __builtin_bit_cast(unsigned, f);
  u += 0x7FFFu + ((u >> 16) & 1u);          // round-nearest-even
  return (short)(u >> 16);
}
__device__ __forceinline__ short8 cvt8(f4 a, f4 b) {
  short8 r;
#pragma unroll
  for (int j = 0; j < 4; ++j) { r[j] = f2bf(a[j]); r[4 + j] = f2bf(b[j]); }
  return r;
}
__device__ __forceinline__ f32x4 mfma16(short8 a, short8 b, f32x4 c) {
  return __builtin_amdgcn_mfma_f32_16x16x32_bf16(a, b, c, 0, 0, 0);
}
__device__ __forceinline__ short8 ldg8(const short* p) {
  return *reinterpret_cast<const short8*>(p);
}
__device__ __forceinline__ f4 ldf4(const float* p) {
  return *reinterpret_cast<const f4*>(p);
}

// async 16B global->LDS
__device__ __forceinline__ void cp16(void* l, const void* g) {
  __builtin_amdgcn_global_load_lds(
      (const __attribute__((address_space(1))) void*)g,
      (__attribute__((address_space(3))) void*)l, 16, 0, 0);
}
#define VWAIT(N) do { asm volatile("s_waitcnt vmcnt(" #N ")" ::: "memory"); \
                      __builtin_amdgcn_sched_barrier(0); } while (0)

// [R][128]-short LDS tile, XOR-swizzled 16B granules
__device__ __forceinline__ short8 rd128s(const short* b, int row, int col) {
  return *reinterpret_cast<const short8*>(b + row * 128 + (col ^ ((row & 7) << 3)));
}
__device__ __forceinline__ void wr128s(short* b, int row, int col8, short8 v) {
  *reinterpret_cast<short8*>(b + row * 128 + (col8 ^ ((row & 7) << 3))) = v;
}
// [16][64]-short per-wave transpose buffer
__device__ __forceinline__ void wr64(short* b, int row, int col, short v) {
  b[row * 64 + (col ^ ((row & 7) << 3))] = v;
}
__device__ __forceinline__ short8 rd64(const short* b, int row, int col) {
  return *reinterpret_cast<const short8*>(b + row * 64 + (col ^ ((row & 7) << 3)));
}

#define LOG2E 1.4426950408889634f
__device__ __forceinline__ float sigm_f(float v) {
  return __builtin_amdgcn_rcpf(1.f + __builtin_amdgcn_exp2f(-v * LOG2E));
}
__device__ __forceinline__ float tanh_f(float v) {
  float t = __builtin_amdgcn_exp2f(v * (2.f * LOG2E));
  return 1.f - 2.f * __builtin_amdgcn_rcpf(t + 1.f);
}

// ---------------------------------------------------------------------------
__global__ void zerok(float* __restrict__ p) {
  const int i = blockIdx.x * blockDim.x + threadIdx.x;
  f4 z = {0.f, 0.f, 0.f, 0.f};
  *reinterpret_cast<f4*>(p + (size_t)i * 8) = z;
  *reinterpret_cast<f4*>(p + (size_t)i * 8 + 4) = z;
}

// ---------------------------------------------------------------------------
__global__ void prep_kernel(const float* __restrict__ W,  const float* __restrict__ W1,
                            const float* __restrict__ W2, const float* __restrict__ W3,
                            const float* __restrict__ U,  const float* __restrict__ U1,
                            const float* __restrict__ U2, const float* __restrict__ U3,
                            short* __restrict__ ws) {
  int i = blockIdx.x * blockDim.x + threadIdx.x;
  float v;
  if (i < 65536) {
    int n = i >> 10, k = i & 1023;
    v = W[k * 64 + n];
  } else if (i < 131072) {
    int j = i - 65536;
    int n = j >> 10, k = j & 1023;
    v = U[k * 64 + n];
  } else {
    int j = i - 131072;
    int sel = j >> 17;
    int jj = j & 131071;
    int n = jj >> 7, k = jj & 127;
    const float* Wk = sel == 0 ? W1 : sel == 1 ? W2 : W3;
    const float* Uk = sel == 0 ? U1 : sel == 1 ? U2 : U3;
    v = (k < 64) ? Wk[k * 1024 + n] : Uk[(k - 64) * 1024 + n];
  }
  ws[i] = f2bf(v);
}

// ---------------------------------------------------------------------------
// k1 (R10): A12f += [x@W | h@U].  Grid 4096 x 128 thr: 32 rows x K-chunk 256.
// No LDS, no barriers; f32 atomic accumulate (A12f pre-zeroed).
// ---------------------------------------------------------------------------
__global__ __launch_bounds__(128, 4) void k1_a12(
    const float* __restrict__ x, const float* __restrict__ h,
    const short* __restrict__ ws, float* __restrict__ A12f) {
  const int tid = threadIdx.x;
  const int w = tid >> 6, l = tid & 63, l15 = l & 15, lg = l >> 4;
  const int rb = blockIdx.x >> 2;
  const int c  = blockIdx.x & 3;
  const int sr = rb * 32 + w * 16;
  const int kb = c * 256;
  const short* Wt = ws;
  const short* Ut = ws + WS_UT;

  const float* xr = x + (size_t)(sr + l15) * 1024 + kb + lg * 8;
  const float* hr = h + (size_t)(sr + l15) * 1024 + kb + lg * 8;

  f32x4 accX[4] = {}, accH[4] = {};
#pragma unroll
  for (int ks = 0; ks < 8; ++ks) {
    f4 xa = ldf4(xr + ks * 32), xb2 = ldf4(xr + ks * 32 + 4);
    f4 ha = ldf4(hr + ks * 32), hb2 = ldf4(hr + ks * 32 + 4);
    short8 ax = cvt8(xa, xb2), ah = cvt8(ha, hb2);
    const int kk = kb + ks * 32 + lg * 8;
#pragma unroll
    for (int cf = 0; cf < 4; ++cf) {
      accX[cf] = mfma16(ax, ldg8(Wt + (size_t)(cf * 16 + l15) * 1024 + kk), accX[cf]);
      accH[cf] = mfma16(ah, ldg8(Ut + (size_t)(cf * 16 + l15) * 1024 + kk), accH[cf]);
    }
  }
#pragma unroll
  for (int cf = 0; cf < 4; ++cf)
#pragma unroll
    for (int j = 0; j < 4; ++j) {
      const size_t row = (size_t)(sr + lg * 4 + j) * 128;
      atomicAdd(&A12f[row + cf * 16 + l15], accX[cf][j]);
      atomicAdd(&A12f[row + 64 + cf * 16 + l15], accH[cf][j]);
    }
}

// ---------------------------------------------------------------------------
// k23 (R8 structure; A12 read as f32): rhU = (sigmoid(pre_r)*h) @ U.  grid 512.
// ---------------------------------------------------------------------------
__global__ __launch_bounds__(256, 2) void k23_rhu(
    const float* __restrict__ h, const float* __restrict__ u1d,
    const float* __restrict__ biasR,
    const short* __restrict__ ws, const float* __restrict__ A12f,
    short* __restrict__ rhU) {
  const short* Ut  = ws + WS_UT;
  const short* P1t = ws + WS_P1T;
  __shared__ __align__(16) float hS[2][4][16 * 64];
  __shared__ __align__(16) short sT[4][16 * 64];

  const int tid = threadIdx.x;
  const int w = tid >> 6, l = tid & 63, l15 = l & 15, lg = l >> 4;
  const int sr = blockIdx.x * 64 + w * 16;

  const int srow = l >> 4;
  const int slin = (l & 15) * 16;

  auto STAGE = [&](int t, int b) {
#pragma unroll
    for (int i = 0; i < 4; ++i) {
      int r = i * 4 + srow;
      int kb = slin ^ ((r & 7) << 4);
      cp16((char*)&hS[b][w][0] + i * 1024,
           (const char*)(h + (size_t)(sr + r) * 1024 + t * 64) + kb);
    }
  };

  short8 a12[4];
#pragma unroll
  for (int k0 = 0; k0 < 4; ++k0) {
    const float* p = A12f + (size_t)(sr + l15) * 128 + k0 * 32 + lg * 8;
    a12[k0] = cvt8(ldf4(p), ldf4(p + 4));
  }

  f32x4 accU[4] = {};
  STAGE(0, 0);
#pragma unroll 1
  for (int tt = 0; tt < 16; ++tt) {
    const int n0 = tt * 64;
    short8 b1[4][4], bu[2][4];
    float d1_[4], br_[4];
#pragma unroll
    for (int ks = 0; ks < 4; ++ks)
#pragma unroll
      for (int cf = 0; cf < 4; ++cf)
        b1[ks][cf] = ldg8(P1t + (size_t)(n0 + cf * 16 + l15) * 128 + ks * 32 + lg * 8);
#pragma unroll
    for (int kk = 0; kk < 2; ++kk)
#pragma unroll
      for (int cf = 0; cf < 4; ++cf)
        bu[kk][cf] = ldg8(Ut + (size_t)(cf * 16 + l15) * 1024 + n0 + kk * 32 + lg * 8);
#pragma unroll
    for (int cf = 0; cf < 4; ++cf) {
      d1_[cf] = u1d[n0 + cf * 16 + l15];
      br_[cf] = biasR[n0 + cf * 16 + l15];
    }
    if (tt < 15) { STAGE(tt + 1, (tt + 1) & 1); VWAIT(4); }
    else         { VWAIT(0); }
    const char* H = (const char*)&hS[tt & 1][w][0];

    float hv[4][4];
#pragma unroll
    for (int cf = 0; cf < 4; ++cf)
#pragma unroll
      for (int j = 0; j < 4; ++j) {
        int rr = lg * 4 + j;
        hv[cf][j] = *(const float*)(H + rr * 256 + ((cf * 64 + l15 * 4) ^ ((rr & 7) << 4)));
      }
    f32x4 accR[4] = {};
#pragma unroll
    for (int ks = 0; ks < 4; ++ks)
#pragma unroll
      for (int cf = 0; cf < 4; ++cf) accR[cf] = mfma16(a12[ks], b1[ks][cf], accR[cf]);
#pragma unroll
    for (int cf = 0; cf < 4; ++cf)
#pragma unroll
      for (int j = 0; j < 4; ++j) {
        float rv = sigm_f(accR[cf][j] + hv[cf][j] * d1_[cf] + br_[cf]);
        wr64(&sT[w][0], lg * 4 + j, cf * 16 + l15, f2bf(rv * hv[cf][j]));
      }
    short8 arh0 = rd64(&sT[w][0], l15, lg * 8);
    short8 arh1 = rd64(&sT[w][0], l15, 32 + lg * 8);
#pragma unroll
    for (int cf = 0; cf < 4; ++cf) accU[cf] = mfma16(arh0, bu[0][cf], accU[cf]);
#pragma unroll
    for (int cf = 0; cf < 4; ++cf) accU[cf] = mfma16(arh1, bu[1][cf], accU[cf]);
  }
#pragma unroll
  for (int cf = 0; cf < 4; ++cf)
#pragma unroll
    for (int j = 0; j < 4; ++j)
      rhU[(size_t)(sr + lg * 4 + j) * 64 + cf * 16 + l15] = f2bf(accU[cf][j]);
}

// ---------------------------------------------------------------------------
// k4 (R8 structure; A12 read as f32): out = z*h + (1-z)*tanh(pre_c).
// Block = 64-col tile x 512-row chunk; P1/P2/P3 stationary in LDS.  grid 1024.
// ---------------------------------------------------------------------------
__global__ __launch_bounds__(256, 2) void k4_out(
    const float* __restrict__ h,
    const float* __restrict__ u1d, const float* __restrict__ u2d,
    const float* __restrict__ u3d,
    const float* __restrict__ biasR, const float* __restrict__ biasZ,
    const float* __restrict__ biasU,
    const short* __restrict__ ws, const float* __restrict__ A12f,
    const short* __restrict__ rhU, float* __restrict__ out) {
  __shared__ __align__(16) short sB1[64 * 128], sB2[64 * 128], sB3[64 * 128];
  __shared__ __align__(16) float hS[2][4][16 * 64];

  const int tid = threadIdx.x;
  const int w = tid >> 6, l = tid & 63, l15 = l & 15, lg = l >> 4;
  const int ct = blockIdx.x & 15, rc = blockIdx.x >> 4;
  const int n0 = ct * 64;

#pragma unroll
  for (int mat = 0; mat < 3; ++mat) {
    const short* srcw = (mat == 0) ? (ws + WS_P1T) : (mat == 1) ? (ws + WS_P2T) : (ws + WS_P3T);
    short* dst = (mat == 0) ? sB1 : (mat == 1) ? sB2 : sB3;
#pragma unroll
    for (int i = 0; i < 4; ++i) {
      int id = tid + i * 256;
      int row = id >> 4, gc = id & 15;
      wr128s(dst, row, gc * 8, ldg8(srcw + (size_t)(n0 + row) * 128 + gc * 8));
    }
  }
  float d1_[4], d2_[4], d3_[4], br_[4], bz_[4], bu_[4];
#pragma unroll
  for (int cf = 0; cf < 4; ++cf) {
    const int cc = n0 + cf * 16 + l15;
    d1_[cf] = u1d[cc]; d2_[cf] = u2d[cc]; d3_[cf] = u3d[cc];
    br_[cf] = biasR[cc]; bz_[cf] = biasZ[cc]; bu_[cf] = biasU[cc];
  }
  __syncthreads();

  const int srow = l >> 4;
  const int slin = (l & 15) * 16;
  auto STAGE = [&](int rnd, int b) {
    const int sb = rc * 512 + rnd * 64 + w * 16;
#pragma unroll
    for (int i = 0; i < 4; ++i) {
      int r = i * 4 + srow;
      int kb = slin ^ ((r & 7) << 4);
      cp16((char*)&hS[b][w][0] + i * 1024,
           (const char*)(h + (size_t)(sb + r) * 1024 + n0) + kb);
    }
  };

  STAGE(0, 0);
#pragma unroll 1
  for (int rnd = 0; rnd < 8; ++rnd) {
    const int sr = rc * 512 + rnd * 64 + w * 16;
    short8 a12[4], arhu[2];
#pragma unroll
    for (int k0 = 0; k0 < 4; ++k0) {
      const float* p = A12f + (size_t)(sr + l15) * 128 + k0 * 32 + lg * 8;
      a12[k0] = cvt8(ldf4(p), ldf4(p + 4));
    }
#pragma unroll
    for (int kk = 0; kk < 2; ++kk)
      arhu[kk] = ldg8(rhU + (size_t)(sr + l15) * 64 + kk * 32 + lg * 8);
    if (rnd < 7) { STAGE(rnd + 1, (rnd + 1) & 1); VWAIT(4); }
    else         { VWAIT(0); }
    const char* H = (const char*)&hS[rnd & 1][w][0];

    float hv[4][4];
#pragma unroll
    for (int cf = 0; cf < 4; ++cf)
#pragma unroll
      for (int j = 0; j < 4; ++j) {
        int rr = lg * 4 + j;
        hv[cf][j] = *(const float*)(H + rr * 256 + ((cf * 64 + l15 * 4) ^ ((rr & 7) << 4)));
      }

    f32x4 aR[4] = {}, aZ[4] = {}, aC[4] = {};
#pragma unroll
    for (int k0 = 0; k0 < 4; ++k0) {
      const short8 a3 = (k0 < 2) ? a12[k0] : arhu[k0 - 2];
#pragma unroll
      for (int cf = 0; cf < 4; ++cf) {
        aR[cf] = mfma16(a12[k0], rd128s(sB1, cf * 16 + l15, k0 * 32 + lg * 8), aR[cf]);
        aZ[cf] = mfma16(a12[k0], rd128s(sB2, cf * 16 + l15, k0 * 32 + lg * 8), aZ[cf]);
        aC[cf] = mfma16(a3,      rd128s(sB3, cf * 16 + l15, k0 * 32 + lg * 8), aC[cf]);
      }
    }
#pragma unroll
    for (int cf = 0; cf < 4; ++cf) {
      const int cc = n0 + cf * 16 + l15;
#pragma unroll
      for (int j = 0; j < 4; ++j) {
        const size_t gi = (size_t)(sr + lg * 4 + j) * 1024 + cc;
        const float hvj = hv[cf][j];
        float rv = sigm_f(aR[cf][j] + hvj * d1_[cf] + br_[cf]);
        float zv = sigm_f(aZ[cf][j] + hvj * d2_[cf] + bz_[cf]);
        float cv = tanh_f(aC[cf][j] + rv * hvj * d3_[cf] + bu_[cf]);
        out[gi] = zv * hvj + (1.f - zv) * cv;
      }
    }
  }
}

extern "C" void kernel_launch(void* const* d_in, const int* in_sizes, int n_in,
                              void* d_out, int out_size, void* d_ws, size_t ws_size,
                              hipStream_t stream) {
  const float* x   = (const float*)d_in[0];
  const float* h   = (const float*)d_in[1];
  const float* W   = (const float*)d_in[2];
  const float* W1  = (const float*)d_in[3];
  const float* W2  = (const float*)d_in[4];
  const float* W3  = (const float*)d_in[5];
  const float* U   = (const float*)d_in[6];
  const float* U1  = (const float*)d_in[7];
  const float* U2  = (const float*)d_in[8];
  const float* U3  = (const float*)d_in[9];
  const float* u1d = (const float*)d_in[10];
  const float* u2d = (const float*)d_in[11];
  const float* u3d = (const float*)d_in[12];
  const float* bR  = (const float*)d_in[13];
  const float* bZ  = (const float*)d_in[14];
  const float* bU  = (const float*)d_in[15];
  short* ws   = (short*)d_ws;
  float* A12f = (float*)((char*)d_ws + A12F_BYTE_OFF);
  short* rhU  = ws + WS_RHU_SHORT;

  zerok<<<2048, 256, 0, stream>>>(A12f);
  prep_kernel<<<2048, 256, 0, stream>>>(W, W1, W2, W3, U, U1, U2, U3, ws);
  k1_a12<<<4096, 128, 0, stream>>>(x, h, ws, A12f);
  k23_rhu<<<512, 256, 0, stream>>>(h, u1d, bR, ws, A12f, rhU);
  k4_out<<<1024, 256, 0, stream>>>(h, u1d, u2d, u3d, bR, bZ, bU, ws, A12f, rhU, (float*)d_out);
}

// Round 13
// 244.776 us; speedup vs baseline: 1.9830x; 1.2816x over previous
//
#include <hip/hip_runtime.h>
#include <hip/hip_bf16.h>

// ---------------------------------------------------------------------------
// myGRUCell low-rank, R13.
//   prep: pack weights bf16 transposed into ws
//   k1  : A12 = [x@W | h@U] bf16.  chunk=64, 32KB LDS, 4 blocks/CU,
//         register-dbuf weights prefetched 1 chunk ahead, VWAIT(12)
//         (counts BOTH the 8 weight ldg8 and 4 cp16 of chunk c+1 -- the
//         R8/R11 pipelines under-counted and stalled every iteration).
//   k23 : rhU = (sigmoid(pre_r)*h) @ U.   R8 byte-identical.
//   k4  : out = z*h+(1-z)*tanh(c).        R8 byte-identical (stationary-B).
// ws layout (shorts): Wt[64][1024] | Ut | P1t[1024][128] | P2t | P3t |
//                     A12[32768][128] | rhU[32768][64]
// ---------------------------------------------------------------------------

typedef __attribute__((ext_vector_type(8))) short short8;
typedef __attribute__((ext_vector_type(4))) float f32x4;
typedef __attribute__((ext_vector_type(4))) float f4;

#define WS_UT   65536
#define WS_P1T  131072
#define WS_P2T  262144
#define WS_P3T  393216
#define WS_A12  524288
#define WS_RHU  4718592

__device__ __forceinline__ short f2bf(float f) {
  unsigned u = __builtin_bit_cast(unsigned, f);
  u += 0x7FFFu + ((u >> 16) & 1u);          // round-nearest-even
  return (short)(u >> 16);
}
__device__ __forceinline__ short8 cvt8(f4 a, f4 b) {
  short8 r;
#pragma unroll
  for (int j = 0; j < 4; ++j) { r[j] = f2bf(a[j]); r[4 + j] = f2bf(b[j]); }
  return r;
}
__device__ __forceinline__ f32x4 mfma16(short8 a, short8 b, f32x4 c) {
  return __builtin_amdgcn_mfma_f32_16x16x32_bf16(a, b, c, 0, 0, 0);
}
__device__ __forceinline__ short8 ldg8(const short* p) {
  return *reinterpret_cast<const short8*>(p);
}
__device__ __forceinline__ f4 ldf4(const float* p) {
  return *reinterpret_cast<const f4*>(p);
}

// async 16B global->LDS
__device__ __forceinline__ void cp16(void* l, const void* g) {
  __builtin_amdgcn_global_load_lds(
      (const __attribute__((address_space(1))) void*)g,
      (__attribute__((address_space(3))) void*)l, 16, 0, 0);
}
#define VWAIT(N) do { asm volatile("s_waitcnt vmcnt(" #N ")" ::: "memory"); \
                      __builtin_amdgcn_sched_barrier(0); } while (0)

// [R][128]-short LDS tile, XOR-swizzled 16B granules
__device__ __forceinline__ short8 rd128s(const short* b, int row, int col) {
  return *reinterpret_cast<const short8*>(b + row * 128 + (col ^ ((row & 7) << 3)));
}
__device__ __forceinline__ void wr128s(short* b, int row, int col8, short8 v) {
  *reinterpret_cast<short8*>(b + row * 128 + (col8 ^ ((row & 7) << 3))) = v;
}
// [16][64]-short per-wave transpose buffer
__device__ __forceinline__ void wr64(short* b, int row, int col, short v) {
  b[row * 64 + (col ^ ((row & 7) << 3))] = v;
}
__device__ __forceinline__ short8 rd64(const short* b, int row, int col) {
  return *reinterpret_cast<const short8*>(b + row * 64 + (col ^ ((row & 7) << 3)));
}

#define LOG2E 1.4426950408889634f
__device__ __forceinline__ float sigm_f(float v) {
  return __builtin_amdgcn_rcpf(1.f + __builtin_amdgcn_exp2f(-v * LOG2E));
}
__device__ __forceinline__ float tanh_f(float v) {
  float t = __builtin_amdgcn_exp2f(v * (2.f * LOG2E));
  return 1.f - 2.f * __builtin_amdgcn_rcpf(t + 1.f);
}

// ---------------------------------------------------------------------------
__global__ void prep_kernel(const float* __restrict__ W,  const float* __restrict__ W1,
                            const float* __restrict__ W2, const float* __restrict__ W3,
                            const float* __restrict__ U,  const float* __restrict__ U1,
                            const float* __restrict__ U2, const float* __restrict__ U3,
                            short* __restrict__ ws) {
  int i = blockIdx.x * blockDim.x + threadIdx.x;
  float v;
  if (i < 65536) {
    int n = i >> 10, k = i & 1023;
    v = W[k * 64 + n];
  } else if (i < 131072) {
    int j = i - 65536;
    int n = j >> 10, k = j & 1023;
    v = U[k * 64 + n];
  } else {
    int j = i - 131072;
    int sel = j >> 17;
    int jj = j & 131071;
    int n = jj >> 7, k = jj & 127;
    const float* Wk = sel == 0 ? W1 : sel == 1 ? W2 : W3;
    const float* Uk = sel == 0 ? U1 : sel == 1 ? U2 : U3;
    v = (k < 64) ? Wk[k * 1024 + n] : Uk[(k - 64) * 1024 + n];
  }
  ws[i] = f2bf(v);
}

// ---------------------------------------------------------------------------
// k1: A12 = [x@W | h@U].  Block 32 rows, 4 waves: wave = (matrix m, row half).
// 16 chunks of 64 f32; stage 4 cp16 + 8 weight ldg8 prefetched 1 ahead.
// grid 1024, 4 blocks/CU (32 KB LDS).
// ---------------------------------------------------------------------------
__global__ __launch_bounds__(256, 4) void k1_a12(
    const float* __restrict__ x, const float* __restrict__ h,
    const short* __restrict__ ws, short* __restrict__ A12) {
  __shared__ __align__(16) float sS[2][4][16 * 64];   // [buf][wave][16r][64f]

  const int tid = threadIdx.x;
  const int w = tid >> 6, l = tid & 63, l15 = l & 15, lg = l >> 4;
  const int m = w >> 1, half = w & 1;
  const int sr = blockIdx.x * 32 + half * 16;
  const float* src = m ? h : x;
  const short* Bt  = ws + m * WS_UT;

  const int srow = l >> 4;            // 0..3: row subgroup
  const int slin = (l & 15) * 16;     // byte within 256B row

  auto STAGE = [&](int c, int b) {
#pragma unroll
    for (int i = 0; i < 4; ++i) {
      int r = i * 4 + srow;
      int kb = slin ^ ((r & 7) << 4);  // pre-swizzled source (rule 21)
      cp16((char*)&sS[b][w][0] + i * 1024,
           (const char*)(src + (size_t)(sr + r) * 1024 + c * 64) + kb);
    }
  };
  auto WLOAD = [&](int c, short8* bw) {
#pragma unroll
    for (int ks = 0; ks < 2; ++ks)
#pragma unroll
      for (int cf = 0; cf < 4; ++cf)
        bw[ks * 4 + cf] =
            ldg8(Bt + (size_t)(cf * 16 + l15) * 1024 + c * 64 + ks * 32 + lg * 8);
  };

  f32x4 acc[4] = {};
  short8 bwb[2][8];
  STAGE(0, 0);
  WLOAD(0, bwb[0]);
#pragma unroll
  for (int c = 0; c < 16; ++c) {
    if (c < 15) {
      WLOAD(c + 1, bwb[(c + 1) & 1]);   // 8 ldg8 (issued FIRST)
      STAGE(c + 1, (c + 1) & 1);        // 4 cp16
      VWAIT(12);                        // retire chunk-c's 12, keep c+1 in flight
    } else {
      VWAIT(0);
    }
    const char* Bb = (const char*)&sS[c & 1][w][0];
    const int s = (l15 & 7) << 4;
    const short8* bw = bwb[c & 1];
#pragma unroll
    for (int ks = 0; ks < 2; ++ks) {
      const int kb0 = (ks * 32 + lg * 8) * 4;
      f4 pa = *(const f4*)(Bb + l15 * 256 + (kb0 ^ s));
      f4 pb = *(const f4*)(Bb + l15 * 256 + ((kb0 + 16) ^ s));
      short8 av = cvt8(pa, pb);
#pragma unroll
      for (int cf = 0; cf < 4; ++cf) acc[cf] = mfma16(av, bw[ks * 4 + cf], acc[cf]);
    }
  }
#pragma unroll
  for (int cf = 0; cf < 4; ++cf)
#pragma unroll
    for (int j = 0; j < 4; ++j)
      A12[(size_t)(sr + lg * 4 + j) * 128 + m * 64 + cf * 16 + l15] = f2bf(acc[cf][j]);
}

// ---------------------------------------------------------------------------
// k23 (R8, unchanged): rhU = (sigmoid(A12@P1 + h*U1d + bR) * h) @ U.  grid 512.
// ---------------------------------------------------------------------------
__global__ __launch_bounds__(256, 2) void k23_rhu(
    const float* __restrict__ h, const float* __restrict__ u1d,
    const float* __restrict__ biasR,
    const short* __restrict__ ws, const short* __restrict__ A12,
    short* __restrict__ rhU) {
  const short* Ut  = ws + WS_UT;
  const short* P1t = ws + WS_P1T;
  __shared__ __align__(16) float hS[2][4][16 * 64];
  __shared__ __align__(16) short sT[4][16 * 64];

  const int tid = threadIdx.x;
  const int w = tid >> 6, l = tid & 63, l15 = l & 15, lg = l >> 4;
  const int sr = blockIdx.x * 64 + w * 16;

  const int srow = l >> 4;
  const int slin = (l & 15) * 16;

  auto STAGE = [&](int t, int b) {
#pragma unroll
    for (int i = 0; i < 4; ++i) {
      int r = i * 4 + srow;
      int kb = slin ^ ((r & 7) << 4);
      cp16((char*)&hS[b][w][0] + i * 1024,
           (const char*)(h + (size_t)(sr + r) * 1024 + t * 64) + kb);
    }
  };

  short8 a12[4];
#pragma unroll
  for (int k0 = 0; k0 < 4; ++k0)
    a12[k0] = ldg8(A12 + (size_t)(sr + l15) * 128 + k0 * 32 + lg * 8);

  f32x4 accU[4] = {};
  STAGE(0, 0);
#pragma unroll 1
  for (int tt = 0; tt < 16; ++tt) {
    const int n0 = tt * 64;
    short8 b1[4][4], bu[2][4];
    float d1_[4], br_[4];
#pragma unroll
    for (int ks = 0; ks < 4; ++ks)
#pragma unroll
      for (int cf = 0; cf < 4; ++cf)
        b1[ks][cf] = ldg8(P1t + (size_t)(n0 + cf * 16 + l15) * 128 + ks * 32 + lg * 8);
#pragma unroll
    for (int kk = 0; kk < 2; ++kk)
#pragma unroll
      for (int cf = 0; cf < 4; ++cf)
        bu[kk][cf] = ldg8(Ut + (size_t)(cf * 16 + l15) * 1024 + n0 + kk * 32 + lg * 8);
#pragma unroll
    for (int cf = 0; cf < 4; ++cf) {
      d1_[cf] = u1d[n0 + cf * 16 + l15];
      br_[cf] = biasR[n0 + cf * 16 + l15];
    }
    if (tt < 15) { STAGE(tt + 1, (tt + 1) & 1); VWAIT(4); }
    else         { VWAIT(0); }
    const char* H = (const char*)&hS[tt & 1][w][0];

    float hv[4][4];
#pragma unroll
    for (int cf = 0; cf < 4; ++cf)
#pragma unroll
      for (int j = 0; j < 4; ++j) {
        int rr = lg * 4 + j;
        hv[cf][j] = *(const float*)(H + rr * 256 + ((cf * 64 + l15 * 4) ^ ((rr & 7) << 4)));
      }
    f32x4 accR[4] = {};
#pragma unroll
    for (int ks = 0; ks < 4; ++ks)
#pragma unroll
      for (int cf = 0; cf < 4; ++cf) accR[cf] = mfma16(a12[ks], b1[ks][cf], accR[cf]);
#pragma unroll
    for (int cf = 0; cf < 4; ++cf)
#pragma unroll
      for (int j = 0; j < 4; ++j) {
        float rv = sigm_f(accR[cf][j] + hv[cf][j] * d1_[cf] + br_[cf]);
        wr64(&sT[w][0], lg * 4 + j, cf * 16 + l15, f2bf(rv * hv[cf][j]));
      }
    short8 arh0 = rd64(&sT[w][0], l15, lg * 8);
    short8 arh1 = rd64(&sT[w][0], l15, 32 + lg * 8);
#pragma unroll
    for (int cf = 0; cf < 4; ++cf) accU[cf] = mfma16(arh0, bu[0][cf], accU[cf]);
#pragma unroll
    for (int cf = 0; cf < 4; ++cf) accU[cf] = mfma16(arh1, bu[1][cf], accU[cf]);
  }
#pragma unroll
  for (int cf = 0; cf < 4; ++cf)
#pragma unroll
    for (int j = 0; j < 4; ++j)
      rhU[(size_t)(sr + lg * 4 + j) * 64 + cf * 16 + l15] = f2bf(accU[cf][j]);
}

// ---------------------------------------------------------------------------
// k4 (R8, unchanged): out = z*h + (1-z)*tanh(pre_c).  Block = 64-col tile x
// 512-row chunk; P1/P2/P3 stationary in LDS.  grid 1024.
// ---------------------------------------------------------------------------
__global__ __launch_bounds__(256, 2) void k4_out(
    const float* __restrict__ h,
    const float* __restrict__ u1d, const float* __restrict__ u2d,
    const float* __restrict__ u3d,
    const float* __restrict__ biasR, const float* __restrict__ biasZ,
    const float* __restrict__ biasU,
    const short* __restrict__ ws, const short* __restrict__ A12,
    const short* __restrict__ rhU, float* __restrict__ out) {
  __shared__ __align__(16) short sB1[64 * 128], sB2[64 * 128], sB3[64 * 128];
  __shared__ __align__(16) float hS[2][4][16 * 64];

  const int tid = threadIdx.x;
  const int w = tid >> 6, l = tid & 63, l15 = l & 15, lg = l >> 4;
  const int ct = blockIdx.x & 15, rc = blockIdx.x >> 4;
  const int n0 = ct * 64;

#pragma unroll
  for (int mat = 0; mat < 3; ++mat) {
    const short* srcw = (mat == 0) ? (ws + WS_P1T) : (mat == 1) ? (ws + WS_P2T) : (ws + WS_P3T);
    short* dst = (mat == 0) ? sB1 : (mat == 1) ? sB2 : sB3;
#pragma unroll
    for (int i = 0; i < 4; ++i) {
      int id = tid + i * 256;
      int row = id >> 4, gc = id & 15;
      wr128s(dst, row, gc * 8, ldg8(srcw + (size_t)(n0 + row) * 128 + gc * 8));
    }
  }
  float d1_[4], d2_[4], d3_[4], br_[4], bz_[4], bu_[4];
#pragma unroll
  for (int cf = 0; cf < 4; ++cf) {
    const int cc = n0 + cf * 16 + l15;
    d1_[cf] = u1d[cc]; d2_[cf] = u2d[cc]; d3_[cf] = u3d[cc];
    br_[cf] = biasR[cc]; bz_[cf] = biasZ[cc]; bu_[cf] = biasU[cc];
  }
  __syncthreads();

  const int srow = l >> 4;
  const int slin = (l & 15) * 16;
  auto STAGE = [&](int rnd, int b) {
    const int sb = rc * 512 + rnd * 64 + w * 16;
#pragma unroll
    for (int i = 0; i < 4; ++i) {
      int r = i * 4 + srow;
      int kb = slin ^ ((r & 7) << 4);
      cp16((char*)&hS[b][w][0] + i * 1024,
           (const char*)(h + (size_t)(sb + r) * 1024 + n0) + kb);
    }
  };

  STAGE(0, 0);
#pragma unroll 1
  for (int rnd = 0; rnd < 8; ++rnd) {
    const int sr = rc * 512 + rnd * 64 + w * 16;
    short8 a12[4], arhu[2];
#pragma unroll
    for (int k0 = 0; k0 < 4; ++k0)
      a12[k0] = ldg8(A12 + (size_t)(sr + l15) * 128 + k0 * 32 + lg * 8);
#pragma unroll
    for (int kk = 0; kk < 2; ++kk)
      arhu[kk] = ldg8(rhU + (size_t)(sr + l15) * 64 + kk * 32 + lg * 8);
    if (rnd < 7) { STAGE(rnd + 1, (rnd + 1) & 1); VWAIT(4); }
    else         { VWAIT(0); }
    const char* H = (const char*)&hS[rnd & 1][w][0];

    float hv[4][4];
#pragma unroll
    for (int cf = 0; cf < 4; ++cf)
#pragma unroll
      for (int j = 0; j < 4; ++j) {
        int rr = lg * 4 + j;
        hv[cf][j] = *(const float*)(H + rr * 256 + ((cf * 64 + l15 * 4) ^ ((rr & 7) << 4)));
      }

    f32x4 aR[4] = {}, aZ[4] = {}, aC[4] = {};
#pragma unroll
    for (int k0 = 0; k0 < 4; ++k0) {
      const short8 a3 = (k0 < 2) ? a12[k0] : arhu[k0 - 2];
#pragma unroll
      for (int cf = 0; cf < 4; ++cf) {
        aR[cf] = mfma16(a12[k0], rd128s(sB1, cf * 16 + l15, k0 * 32 + lg * 8), aR[cf]);
        aZ[cf] = mfma16(a12[k0], rd128s(sB2, cf * 16 + l15, k0 * 32 + lg * 8), aZ[cf]);
        aC[cf] = mfma16(a3,      rd128s(sB3, cf * 16 + l15, k0 * 32 + lg * 8), aC[cf]);
      }
    }
#pragma unroll
    for (int cf = 0; cf < 4; ++cf) {
      const int cc = n0 + cf * 16 + l15;
#pragma unroll
      for (int j = 0; j < 4; ++j) {
        const size_t gi = (size_t)(sr + lg * 4 + j) * 1024 + cc;
        const float hvj = hv[cf][j];
        float rv = sigm_f(aR[cf][j] + hvj * d1_[cf] + br_[cf]);
        float zv = sigm_f(aZ[cf][j] + hvj * d2_[cf] + bz_[cf]);
        float cv = tanh_f(aC[cf][j] + rv * hvj * d3_[cf] + bu_[cf]);
        out[gi] = zv * hvj + (1.f - zv) * cv;
      }
    }
  }
}

extern "C" void kernel_launch(void* const* d_in, const int* in_sizes, int n_in,
                              void* d_out, int out_size, void* d_ws, size_t ws_size,
                              hipStream_t stream) {
  const float* x   = (const float*)d_in[0];
  const float* h   = (const float*)d_in[1];
  const float* W   = (const float*)d_in[2];
  const float* W1  = (const float*)d_in[3];
  const float* W2  = (const float*)d_in[4];
  const float* W3  = (const float*)d_in[5];
  const float* U   = (const float*)d_in[6];
  const float* U1  = (const float*)d_in[7];
  const float* U2  = (const float*)d_in[8];
  const float* U3  = (const float*)d_in[9];
  const float* u1d = (const float*)d_in[10];
  const float* u2d = (const float*)d_in[11];
  const float* u3d = (const float*)d_in[12];
  const float* bR  = (const float*)d_in[13];
  const float* bZ  = (const float*)d_in[14];
  const float* bU  = (const float*)d_in[15];
  short* ws  = (short*)d_ws;
  short* A12 = ws + WS_A12;
  short* rhU = ws + WS_RHU;

  prep_kernel<<<2048, 256, 0, stream>>>(W, W1, W2, W3, U, U1, U2, U3, ws);
  k1_a12<<<1024, 256, 0, stream>>>(x, h, ws, A12);
  k23_rhu<<<512, 256, 0, stream>>>(h, u1d, bR, ws, A12, rhU);
  k4_out<<<1024, 256, 0, stream>>>(h, u1d, u2d, u3d, bR, bZ, bU, ws, A12, rhU, (float*)d_out);
}

// Round 14
// 240.429 us; speedup vs baseline: 2.0189x; 1.0181x over previous
//
#include <hip/hip_runtime.h>
#include <hip/hip_bf16.h>

// ---------------------------------------------------------------------------
// myGRUCell low-rank, R14 = R13 with k23 replaced by R7's col-split version.
//   prep: pack weights bf16 transposed into ws
//   k1  : A12 = [x@W | h@U] bf16  (R13: chunk 64, reg-dbuf weights, VWAIT(12))
//   k23 : rhU = (sigmoid(pre_r)*h) @ U  (R7: grid 1024, 2 strips x 2 col-
//         halves, 8 tiles/wave, LDS pair-reduce, 16 waves/CU)
//   k4  : out = z*h+(1-z)*tanh(c)  (R8/R13 stationary-B)
// ws layout (shorts): Wt[64][1024] | Ut | P1t[1024][128] | P2t | P3t |
//                     A12[32768][128] | rhU[32768][64]
// ---------------------------------------------------------------------------

typedef __attribute__((ext_vector_type(8))) short short8;
typedef __attribute__((ext_vector_type(4))) float f32x4;
typedef __attribute__((ext_vector_type(4))) float f4;

#define WS_UT   65536
#define WS_P1T  131072
#define WS_P2T  262144
#define WS_P3T  393216
#define WS_A12  524288
#define WS_RHU  4718592

__device__ __forceinline__ short f2bf(float f) {
  unsigned u = __builtin_bit_cast(unsigned, f);
  u += 0x7FFFu + ((u >> 16) & 1u);          // round-nearest-even
  return (short)(u >> 16);
}
__device__ __forceinline__ short8 cvt8(f4 a, f4 b) {
  short8 r;
#pragma unroll
  for (int j = 0; j < 4; ++j) { r[j] = f2bf(a[j]); r[4 + j] = f2bf(b[j]); }
  return r;
}
__device__ __forceinline__ f32x4 mfma16(short8 a, short8 b, f32x4 c) {
  return __builtin_amdgcn_mfma_f32_16x16x32_bf16(a, b, c, 0, 0, 0);
}
__device__ __forceinline__ short8 ldg8(const short* p) {
  return *reinterpret_cast<const short8*>(p);
}
__device__ __forceinline__ f4 ldf4(const float* p) {
  return *reinterpret_cast<const f4*>(p);
}

// async 16B global->LDS
__device__ __forceinline__ void cp16(void* l, const void* g) {
  __builtin_amdgcn_global_load_lds(
      (const __attribute__((address_space(1))) void*)g,
      (__attribute__((address_space(3))) void*)l, 16, 0, 0);
}
#define VWAIT(N) do { asm volatile("s_waitcnt vmcnt(" #N ")" ::: "memory"); \
                      __builtin_amdgcn_sched_barrier(0); } while (0)

// [R][128]-short LDS tile, XOR-swizzled 16B granules
__device__ __forceinline__ short8 rd128s(const short* b, int row, int col) {
  return *reinterpret_cast<const short8*>(b + row * 128 + (col ^ ((row & 7) << 3)));
}
__device__ __forceinline__ void wr128s(short* b, int row, int col8, short8 v) {
  *reinterpret_cast<short8*>(b + row * 128 + (col8 ^ ((row & 7) << 3))) = v;
}
// [16][64]-short per-wave transpose buffer
__device__ __forceinline__ void wr64(short* b, int row, int col, short v) {
  b[row * 64 + (col ^ ((row & 7) << 3))] = v;
}
__device__ __forceinline__ short8 rd64(const short* b, int row, int col) {
  return *reinterpret_cast<const short8*>(b + row * 64 + (col ^ ((row & 7) << 3)));
}

#define LOG2E 1.4426950408889634f
__device__ __forceinline__ float sigm_f(float v) {
  return __builtin_amdgcn_rcpf(1.f + __builtin_amdgcn_exp2f(-v * LOG2E));
}
__device__ __forceinline__ float tanh_f(float v) {
  float t = __builtin_amdgcn_exp2f(v * (2.f * LOG2E));
  return 1.f - 2.f * __builtin_amdgcn_rcpf(t + 1.f);
}

// ---------------------------------------------------------------------------
__global__ void prep_kernel(const float* __restrict__ W,  const float* __restrict__ W1,
                            const float* __restrict__ W2, const float* __restrict__ W3,
                            const float* __restrict__ U,  const float* __restrict__ U1,
                            const float* __restrict__ U2, const float* __restrict__ U3,
                            short* __restrict__ ws) {
  int i = blockIdx.x * blockDim.x + threadIdx.x;
  float v;
  if (i < 65536) {
    int n = i >> 10, k = i & 1023;
    v = W[k * 64 + n];
  } else if (i < 131072) {
    int j = i - 65536;
    int n = j >> 10, k = j & 1023;
    v = U[k * 64 + n];
  } else {
    int j = i - 131072;
    int sel = j >> 17;
    int jj = j & 131071;
    int n = jj >> 7, k = jj & 127;
    const float* Wk = sel == 0 ? W1 : sel == 1 ? W2 : W3;
    const float* Uk = sel == 0 ? U1 : sel == 1 ? U2 : U3;
    v = (k < 64) ? Wk[k * 1024 + n] : Uk[(k - 64) * 1024 + n];
  }
  ws[i] = f2bf(v);
}

// ---------------------------------------------------------------------------
// k1 (R13): A12 = [x@W | h@U].  Block 32 rows, 4 waves; 16 chunks of 64 f32;
// weights reg-dbuf prefetched 1 chunk ahead; VWAIT(12).  grid 1024.
// ---------------------------------------------------------------------------
__global__ __launch_bounds__(256, 4) void k1_a12(
    const float* __restrict__ x, const float* __restrict__ h,
    const short* __restrict__ ws, short* __restrict__ A12) {
  __shared__ __align__(16) float sS[2][4][16 * 64];

  const int tid = threadIdx.x;
  const int w = tid >> 6, l = tid & 63, l15 = l & 15, lg = l >> 4;
  const int m = w >> 1, half = w & 1;
  const int sr = blockIdx.x * 32 + half * 16;
  const float* src = m ? h : x;
  const short* Bt  = ws + m * WS_UT;

  const int srow = l >> 4;
  const int slin = (l & 15) * 16;

  auto STAGE = [&](int c, int b) {
#pragma unroll
    for (int i = 0; i < 4; ++i) {
      int r = i * 4 + srow;
      int kb = slin ^ ((r & 7) << 4);
      cp16((char*)&sS[b][w][0] + i * 1024,
           (const char*)(src + (size_t)(sr + r) * 1024 + c * 64) + kb);
    }
  };
  auto WLOAD = [&](int c, short8* bw) {
#pragma unroll
    for (int ks = 0; ks < 2; ++ks)
#pragma unroll
      for (int cf = 0; cf < 4; ++cf)
        bw[ks * 4 + cf] =
            ldg8(Bt + (size_t)(cf * 16 + l15) * 1024 + c * 64 + ks * 32 + lg * 8);
  };

  f32x4 acc[4] = {};
  short8 bwb[2][8];
  STAGE(0, 0);
  WLOAD(0, bwb[0]);
#pragma unroll
  for (int c = 0; c < 16; ++c) {
    if (c < 15) {
      WLOAD(c + 1, bwb[(c + 1) & 1]);
      STAGE(c + 1, (c + 1) & 1);
      VWAIT(12);
    } else {
      VWAIT(0);
    }
    const char* Bb = (const char*)&sS[c & 1][w][0];
    const int s = (l15 & 7) << 4;
    const short8* bw = bwb[c & 1];
#pragma unroll
    for (int ks = 0; ks < 2; ++ks) {
      const int kb0 = (ks * 32 + lg * 8) * 4;
      f4 pa = *(const f4*)(Bb + l15 * 256 + (kb0 ^ s));
      f4 pb = *(const f4*)(Bb + l15 * 256 + ((kb0 + 16) ^ s));
      short8 av = cvt8(pa, pb);
#pragma unroll
      for (int cf = 0; cf < 4; ++cf) acc[cf] = mfma16(av, bw[ks * 4 + cf], acc[cf]);
    }
  }
#pragma unroll
  for (int cf = 0; cf < 4; ++cf)
#pragma unroll
    for (int j = 0; j < 4; ++j)
      A12[(size_t)(sr + lg * 4 + j) * 128 + m * 64 + cf * 16 + l15] = f2bf(acc[cf][j]);
}

// ---------------------------------------------------------------------------
// k23 (R7): rhU = (sigmoid(A12@P1 + h*U1d + bR) * h) @ U.
// Wave = 16 rows x 512-col half; 8 tiles of 64 cols; per-wave LDS transpose;
// one barrier + LDS pair-reduce of rhU partials.  grid 1024 x 256.
// ---------------------------------------------------------------------------
__global__ __launch_bounds__(256, 4) void k23_rhu(
    const float* __restrict__ h, const float* __restrict__ u1d,
    const float* __restrict__ biasR,
    const short* __restrict__ ws, const short* __restrict__ A12,
    short* __restrict__ rhU) {
  const short* Ut  = ws + WS_UT;
  const short* P1t = ws + WS_P1T;
  __shared__ __align__(16) short sT[4][2][16 * 64];   // per-wave transpose dbuf
  __shared__ __align__(16) float sRed[2][2][16 * 64]; // [strip][colhalf] partials

  const int tid = threadIdx.x;
  const int w   = tid >> 6, l = tid & 63, l15 = l & 15, lg = l >> 4;
  const int s   = w >> 1;        // strip in block
  const int ch  = w & 1;         // col half
  const int sr  = blockIdx.x * 32 + s * 16;

  short8 a12[4];
#pragma unroll
  for (int k0 = 0; k0 < 4; ++k0)
    a12[k0] = ldg8(A12 + (size_t)(sr + l15) * 128 + k0 * 32 + lg * 8);

  f32x4 accU[4] = {};
#pragma unroll 1
  for (int tt = 0; tt < 8; ++tt) {
    const int n0 = ch * 512 + tt * 64;

    float hv[4][4];
#pragma unroll
    for (int cf = 0; cf < 4; ++cf)
#pragma unroll
      for (int j = 0; j < 4; ++j)
        hv[cf][j] = h[(size_t)(sr + lg * 4 + j) * 1024 + n0 + cf * 16 + l15];

    f32x4 accR[4] = {};
#pragma unroll
    for (int k0 = 0; k0 < 4; ++k0)
#pragma unroll
      for (int cf = 0; cf < 4; ++cf)
        accR[cf] = mfma16(a12[k0],
            ldg8(P1t + (size_t)(n0 + cf * 16 + l15) * 128 + k0 * 32 + lg * 8),
            accR[cf]);

    short* sw = &sT[w][tt & 1][0];
#pragma unroll
    for (int cf = 0; cf < 4; ++cf) {
      const int cc = n0 + cf * 16 + l15;
      const float d1 = u1d[cc], b_r = biasR[cc];
#pragma unroll
      for (int j = 0; j < 4; ++j) {
        float rv = sigm_f(accR[cf][j] + hv[cf][j] * d1 + b_r);
        wr64(sw, lg * 4 + j, cf * 16 + l15, f2bf(rv * hv[cf][j]));
      }
    }
    // wave-coherent RAW through LDS (lgkmcnt only; R5-R13 proven)
    short8 arh0 = rd64(sw, l15, lg * 8);
    short8 arh1 = rd64(sw, l15, 32 + lg * 8);
#pragma unroll
    for (int cf = 0; cf < 4; ++cf)
      accU[cf] = mfma16(arh0,
          ldg8(Ut + (size_t)(cf * 16 + l15) * 1024 + n0 + lg * 8), accU[cf]);
#pragma unroll
    for (int cf = 0; cf < 4; ++cf)
      accU[cf] = mfma16(arh1,
          ldg8(Ut + (size_t)(cf * 16 + l15) * 1024 + n0 + 32 + lg * 8), accU[cf]);
  }

  // pair-reduce partials across col halves
  {
    float* fT = &sRed[s][ch][0];
#pragma unroll
    for (int cf = 0; cf < 4; ++cf)
#pragma unroll
      for (int j = 0; j < 4; ++j) {
        int row = lg * 4 + j, col = cf * 16 + l15;
        fT[row * 64 + (col ^ ((row & 7) << 2))] = accU[cf][j];
      }
  }
  __syncthreads();
  if (ch == 0) {
    const float* f0 = &sRed[s][0][0];
    const float* f1 = &sRed[s][1][0];
#pragma unroll
    for (int cf = 0; cf < 4; ++cf)
#pragma unroll
      for (int j = 0; j < 4; ++j) {
        int row = lg * 4 + j, col = cf * 16 + l15;
        int idx = row * 64 + (col ^ ((row & 7) << 2));
        rhU[(size_t)(sr + row) * 64 + col] = f2bf(f0[idx] + f1[idx]);
      }
  }
}

// ---------------------------------------------------------------------------
// k4 (R8/R13): out = z*h + (1-z)*tanh(pre_c).  Block = 64-col tile x 512-row
// chunk; P1/P2/P3 stationary in LDS.  grid 1024.
// ---------------------------------------------------------------------------
__global__ __launch_bounds__(256, 2) void k4_out(
    const float* __restrict__ h,
    const float* __restrict__ u1d, const float* __restrict__ u2d,
    const float* __restrict__ u3d,
    const float* __restrict__ biasR, const float* __restrict__ biasZ,
    const float* __restrict__ biasU,
    const short* __restrict__ ws, const short* __restrict__ A12,
    const short* __restrict__ rhU, float* __restrict__ out) {
  __shared__ __align__(16) short sB1[64 * 128], sB2[64 * 128], sB3[64 * 128];
  __shared__ __align__(16) float hS[2][4][16 * 64];

  const int tid = threadIdx.x;
  const int w = tid >> 6, l = tid & 63, l15 = l & 15, lg = l >> 4;
  const int ct = blockIdx.x & 15, rc = blockIdx.x >> 4;
  const int n0 = ct * 64;

#pragma unroll
  for (int mat = 0; mat < 3; ++mat) {
    const short* srcw = (mat == 0) ? (ws + WS_P1T) : (mat == 1) ? (ws + WS_P2T) : (ws + WS_P3T);
    short* dst = (mat == 0) ? sB1 : (mat == 1) ? sB2 : sB3;
#pragma unroll
    for (int i = 0; i < 4; ++i) {
      int id = tid + i * 256;
      int row = id >> 4, gc = id & 15;
      wr128s(dst, row, gc * 8, ldg8(srcw + (size_t)(n0 + row) * 128 + gc * 8));
    }
  }
  float d1_[4], d2_[4], d3_[4], br_[4], bz_[4], bu_[4];
#pragma unroll
  for (int cf = 0; cf < 4; ++cf) {
    const int cc = n0 + cf * 16 + l15;
    d1_[cf] = u1d[cc]; d2_[cf] = u2d[cc]; d3_[cf] = u3d[cc];
    br_[cf] = biasR[cc]; bz_[cf] = biasZ[cc]; bu_[cf] = biasU[cc];
  }
  __syncthreads();

  const int srow = l >> 4;
  const int slin = (l & 15) * 16;
  auto STAGE = [&](int rnd, int b) {
    const int sb = rc * 512 + rnd * 64 + w * 16;
#pragma unroll
    for (int i = 0; i < 4; ++i) {
      int r = i * 4 + srow;
      int kb = slin ^ ((r & 7) << 4);
      cp16((char*)&hS[b][w][0] + i * 1024,
           (const char*)(h + (size_t)(sb + r) * 1024 + n0) + kb);
    }
  };

  STAGE(0, 0);
#pragma unroll 1
  for (int rnd = 0; rnd < 8; ++rnd) {
    const int sr = rc * 512 + rnd * 64 + w * 16;
    short8 a12[4], arhu[2];
#pragma unroll
    for (int k0 = 0; k0 < 4; ++k0)
      a12[k0] = ldg8(A12 + (size_t)(sr + l15) * 128 + k0 * 32 + lg * 8);
#pragma unroll
    for (int kk = 0; kk < 2; ++kk)
      arhu[kk] = ldg8(rhU + (size_t)(sr + l15) * 64 + kk * 32 + lg * 8);
    if (rnd < 7) { STAGE(rnd + 1, (rnd + 1) & 1); VWAIT(4); }
    else         { VWAIT(0); }
    const char* H = (const char*)&hS[rnd & 1][w][0];

    float hv[4][4];
#pragma unroll
    for (int cf = 0; cf < 4; ++cf)
#pragma unroll
      for (int j = 0; j < 4; ++j) {
        int rr = lg * 4 + j;
        hv[cf][j] = *(const float*)(H + rr * 256 + ((cf * 64 + l15 * 4) ^ ((rr & 7) << 4)));
      }

    f32x4 aR[4] = {}, aZ[4] = {}, aC[4] = {};
#pragma unroll
    for (int k0 = 0; k0 < 4; ++k0) {
      const short8 a3 = (k0 < 2) ? a12[k0] : arhu[k0 - 2];
#pragma unroll
      for (int cf = 0; cf < 4; ++cf) {
        aR[cf] = mfma16(a12[k0], rd128s(sB1, cf * 16 + l15, k0 * 32 + lg * 8), aR[cf]);
        aZ[cf] = mfma16(a12[k0], rd128s(sB2, cf * 16 + l15, k0 * 32 + lg * 8), aZ[cf]);
        aC[cf] = mfma16(a3,      rd128s(sB3, cf * 16 + l15, k0 * 32 + lg * 8), aC[cf]);
      }
    }
#pragma unroll
    for (int cf = 0; cf < 4; ++cf) {
      const int cc = n0 + cf * 16 + l15;
#pragma unroll
      for (int j = 0; j < 4; ++j) {
        const size_t gi = (size_t)(sr + lg * 4 + j) * 1024 + cc;
        const float hvj = hv[cf][j];
        float rv = sigm_f(aR[cf][j] + hvj * d1_[cf] + br_[cf]);
        float zv = sigm_f(aZ[cf][j] + hvj * d2_[cf] + bz_[cf]);
        float cv = tanh_f(aC[cf][j] + rv * hvj * d3_[cf] + bu_[cf]);
        out[gi] = zv * hvj + (1.f - zv) * cv;
      }
    }
  }
}

extern "C" void kernel_launch(void* const* d_in, const int* in_sizes, int n_in,
                              void* d_out, int out_size, void* d_ws, size_t ws_size,
                              hipStream_t stream) {
  const float* x   = (const float*)d_in[0];
  const float* h   = (const float*)d_in[1];
  const float* W   = (const float*)d_in[2];
  const float* W1  = (const float*)d_in[3];
  const float* W2  = (const float*)d_in[4];
  const float* W3  = (const float*)d_in[5];
  const float* U   = (const float*)d_in[6];
  const float* U1  = (const float*)d_in[7];
  const float* U2  = (const float*)d_in[8];
  const float* U3  = (const float*)d_in[9];
  const float* u1d = (const float*)d_in[10];
  const float* u2d = (const float*)d_in[11];
  const float* u3d = (const float*)d_in[12];
  const float* bR  = (const float*)d_in[13];
  const float* bZ  = (const float*)d_in[14];
  const float* bU  = (const float*)d_in[15];
  short* ws  = (short*)d_ws;
  short* A12 = ws + WS_A12;
  short* rhU = ws + WS_RHU;

  prep_kernel<<<2048, 256, 0, stream>>>(W, W1, W2, W3, U, U1, U2, U3, ws);
  k1_a12<<<1024, 256, 0, stream>>>(x, h, ws, A12);
  k23_rhu<<<1024, 256, 0, stream>>>(h, u1d, bR, ws, A12, rhU);
  k4_out<<<1024, 256, 0, stream>>>(h, u1d, u2d, u3d, bR, bZ, bU, ws, A12, rhU, (float*)d_out);
}